// Round 5
// baseline (536.867 us; speedup 1.0000x reference)
//
#include <hip/hip_runtime.h>
#include <hip/hip_bf16.h>

#define DI __device__ __forceinline__

typedef float f32x4 __attribute__((ext_vector_type(4)));
typedef short s16x8 __attribute__((ext_vector_type(8)));

constexpr int N_NODES = 50000;
constexpr int N_EDGES = 400000;
constexpr int G       = 64;
constexpr int C       = 32;
constexpr float BN_EPS = 1e-5f;

// ---------------- workspace layout (bytes) ----------------
constexpr size_t OFF_WH    = 0;                                   // [960][128] bf16 (Wl,Wr,We)
constexpr size_t OFF_SCALE = 245760;                              // [128] f32
constexpr size_t OFF_SHIFT = OFF_SCALE + 512;                     // [128] f32
constexpr size_t OFF_Y     = OFF_SHIFT + 512;                     // [N][640] bf16 (xl|xr, PAIRED)
constexpr size_t OFF_ALPHA = OFF_Y + (size_t)N_NODES * 640 * 2;   // [E][10] f32 (exp(alpha))
constexpr size_t OFF_DENOM = OFF_ALPHA + (size_t)N_EDGES * 10 * 4;// [N][10] f32
constexpr size_t OFF_ACC   = OFF_DENOM + (size_t)N_NODES * 10 * 4;// [N][32] f32
constexpr size_t OFF_POOL  = OFF_ACC + (size_t)N_NODES * 32 * 4;  // [64][32] f32
constexpr size_t OFF_CNT   = OFF_POOL + (size_t)G * C * 4;        // [64] f32

// y PAIRED layout: u32[n*320 + headg*16 + s] holds bf16 cols (headg*32+s, headg*32+16+s),
// headg 0..9 = xl heads, 10..19 = xr heads.

DI float bf2f(unsigned short u) {
    unsigned int x = ((unsigned int)u) << 16;
    float f; __builtin_memcpy(&f, &x, 4); return f;
}
DI unsigned short f2bf(float f) {   // round-to-nearest-even (finite inputs)
    unsigned int x; __builtin_memcpy(&x, &f, 4);
    x += 0x7FFFu + ((x >> 16) & 1u);
    return (unsigned short)(x >> 16);
}
DI float lo16(unsigned int u) {
    unsigned int x = u << 16; float f; __builtin_memcpy(&f, &x, 4); return f;
}
DI float hi16(unsigned int u) {
    unsigned int x = u & 0xffff0000u; float f; __builtin_memcpy(&f, &x, 4); return f;
}
DI unsigned int cvtpk(float a, float b) {  // v_cvt_pk_bf16_f32: lo=a, hi=b
    unsigned int r;
    asm("v_cvt_pk_bf16_f32 %0, %1, %2" : "=v"(r) : "v"(a), "v"(b));
    return r;
}
// XOR swizzle inside a 256B row (A tile: row stride 256B)
DI int swzA(int row, int kb) { return row * 256 + (kb ^ ((row & 7) << 4)); }

// ---------------- init ----------------
__global__ void k_init(const float* __restrict__ Wl, const float* __restrict__ Wr,
                       const float* __restrict__ We, const float* __restrict__ gamma,
                       const float* __restrict__ beta, const float* __restrict__ mean,
                       const float* __restrict__ var,
                       unsigned short* __restrict__ Wh, float* __restrict__ scale,
                       float* __restrict__ shift, float* __restrict__ denom,
                       float* __restrict__ accC, float* __restrict__ pooled,
                       float* __restrict__ cnt)
{
    int idx0 = blockIdx.x * blockDim.x + threadIdx.x;
    int stride = gridDim.x * blockDim.x;
    for (int i = idx0; i < 960 * 128; i += stride) {
        float v;
        if (i < 320 * 128)      v = Wl[i];
        else if (i < 640 * 128) v = Wr[i - 320 * 128];
        else                    v = We[i - 640 * 128];
        Wh[i] = f2bf(v);
    }
    for (int i = idx0; i < 128; i += stride) {
        float sc = gamma[i] * rsqrtf(var[i] + BN_EPS);
        scale[i] = sc;
        shift[i] = beta[i] - mean[i] * sc;
    }
    for (int i = idx0; i < N_NODES * 10; i += stride) denom[i] = 0.f;
    for (int i = idx0; i < N_NODES * 32; i += stride) accC[i] = 0.f;
    for (int i = idx0; i < G * C; i += stride) pooled[i] = 0.f;
    for (int i = idx0; i < G; i += stride) cnt[i] = 0.f;
}

// ---------------- node GEMM: y[n] = bn(x) @ [Wl;Wr].T + [bl;br] (paired bf16)
// LDS: A 16KB + B K=32-chunk 20KB = 36KB -> 4 blocks/CU.
__global__ __launch_bounds__(512, 8)
void k_node_gemm(const float* __restrict__ x, const unsigned short* __restrict__ Wh,
                 const float* __restrict__ scale, const float* __restrict__ shift,
                 const float* __restrict__ bl, const float* __restrict__ br,
                 unsigned short* __restrict__ y)
{
    __shared__ unsigned char smem[36864];
    unsigned char* sA = smem;             // [64][256B] swizzled
    unsigned char* sB = smem + 16384;     // [4 k-frag][320 col][16B]
    const int tid = threadIdx.x;
    const int n0 = blockIdx.x * 64;
    const int ch = blockIdx.y;            // 0: Wl half, 1: Wr half
    const int wrow0 = ch * 320;

    // stage A (x with BN fused), fp32 -> bf16
#pragma unroll
    for (int it = 0; it < 4; ++it) {
        int c = tid + it * 512;           // 0..2047
        int row = c >> 5, q = c & 31;
        int n = n0 + row;
        float4 v = make_float4(0.f, 0.f, 0.f, 0.f);
        if (n < N_NODES) v = *reinterpret_cast<const float4*>(x + (size_t)n * 128 + q * 4);
        float x0 = v.x * scale[q * 4 + 0] + shift[q * 4 + 0];
        float x1 = v.y * scale[q * 4 + 1] + shift[q * 4 + 1];
        float x2 = v.z * scale[q * 4 + 2] + shift[q * 4 + 2];
        float x3 = v.w * scale[q * 4 + 3] + shift[q * 4 + 3];
        uint2 pk = make_uint2(cvtpk(x0, x1), cvtpk(x2, x3));
        *reinterpret_cast<uint2*>(sA + swzA(row, q * 8)) = pk;
    }
    __syncthreads();

    const int w = tid >> 6, l = tid & 63;
    const int rw = (w & 3) * 16;
    const int cq = (w >> 2) * 160;
    const int l15 = l & 15, l4 = l >> 4;

    f32x4 acc[10];
#pragma unroll
    for (int f = 0; f < 10; ++f) acc[f] = (f32x4){0.f, 0.f, 0.f, 0.f};

    for (int kq = 0; kq < 4; ++kq) {
        if (kq) __syncthreads();          // prev MFMA done reading sB
#pragma unroll
        for (int it = 0; it < 5; ++it) {
            int id = tid + it * 512;      // 0..2559
            int col = id >> 3, rem = id & 7;
            int u = rem >> 1, h4 = rem & 1;
            uint2 v = *reinterpret_cast<const uint2*>(
                Wh + (size_t)(wrow0 + col) * 128 + kq * 32 + u * 8 + h4 * 4);
            *reinterpret_cast<uint2*>(sB + u * 5120 + col * 16 + h4 * 8) = v;
        }
        __syncthreads();
        s16x8 a = *reinterpret_cast<const s16x8*>(sA + swzA(rw + l15, kq * 64 + l4 * 16));
#pragma unroll
        for (int f = 0; f < 10; ++f) {
            s16x8 b = *reinterpret_cast<const s16x8*>(sB + l4 * 5120 + (cq + f * 16 + l15) * 16);
            acc[f] = __builtin_amdgcn_mfma_f32_16x16x32_bf16(a, b, acc[f], 0, 0, 0);
        }
    }

    const float* bias = ch ? br : bl;
    unsigned int* y32 = reinterpret_cast<unsigned int*>(y);
#pragma unroll
    for (int fp = 0; fp < 5; ++fp) {
        int lc0 = cq + fp * 32 + l15;     // low col of the pair within this half
        float b0 = bias[lc0], b1 = bias[lc0 + 16];
        int headg = ch * 10 + (cq >> 5) + fp;
#pragma unroll
        for (int j = 0; j < 4; ++j) {
            int n = n0 + rw + l4 * 4 + j;
            if (n < N_NODES)
                y32[(size_t)n * 320 + headg * 16 + l15] =
                    cvtpk(acc[2 * fp][j] + b0, acc[2 * fp + 1][j] + b1);
        }
    }
}

// ---------------- edge GEMM + GATv2 scoring ----------------
// LDS 36KB (4 blocks/CU): A 16KB + B-chunk 20KB during GEMM; then two
// spill/score passes of 32 rows (648B stride) aliased over A+B.
__global__ __launch_bounds__(512, 8)
void k_edge(const float* __restrict__ eattr, const unsigned short* __restrict__ Wh,
            const unsigned short* __restrict__ y, const int* __restrict__ ei,
            const float* __restrict__ att, float* __restrict__ alphaE,
            float* __restrict__ denom)
{
    __shared__ unsigned char smem[36864];
    unsigned char* sA = smem;             // [64][256B] swizzled (GEMM phase)
    unsigned char* sB = smem + 16384;     // [4][320][16B] (GEMM phase)
    unsigned char* sE = smem;             // [32][648B] spill (per pass)
    const int tid = threadIdx.x;
    const int e0 = blockIdx.x * 64;
    const int w = tid >> 6, l = tid & 63;
    const int rw = (w & 3) * 16;
    const int cq = (w >> 2) * 160;
    const int l15 = l & 15, l4 = l >> 4;
    const int q16 = l & 15;
    const unsigned int* y32 = reinterpret_cast<const unsigned int*>(y);

    // stage A (edge_attr fp32 -> bf16); E = 6250*64 exactly, no bounds needed
#pragma unroll
    for (int it = 0; it < 4; ++it) {
        int c = tid + it * 512;
        int row = c >> 5, q = c & 31;
        float4 v = *reinterpret_cast<const float4*>(eattr + (size_t)(e0 + row) * 128 + q * 4);
        uint2 pk = make_uint2(cvtpk(v.x, v.y), cvtpk(v.z, v.w));
        *reinterpret_cast<uint2*>(sA + swzA(row, q * 8)) = pk;
    }
    __syncthreads();

    f32x4 acc[10];
#pragma unroll
    for (int f = 0; f < 10; ++f) acc[f] = (f32x4){0.f, 0.f, 0.f, 0.f};

    for (int kq = 0; kq < 4; ++kq) {
        if (kq) __syncthreads();
#pragma unroll
        for (int it = 0; it < 5; ++it) {
            int id = tid + it * 512;      // 0..2559
            int col = id >> 3, rem = id & 7;
            int u = rem >> 1, h4 = rem & 1;
            uint2 v = *reinterpret_cast<const uint2*>(
                Wh + (size_t)(640 + col) * 128 + kq * 32 + u * 8 + h4 * 4);
            *reinterpret_cast<uint2*>(sB + u * 5120 + col * 16 + h4 * 8) = v;
        }
        __syncthreads();
        s16x8 a = *reinterpret_cast<const s16x8*>(sA + swzA(rw + l15, kq * 64 + l4 * 16));
#pragma unroll
        for (int f = 0; f < 10; ++f) {
            s16x8 b = *reinterpret_cast<const s16x8*>(sB + l4 * 5120 + (cq + f * 16 + l15) * 16);
            acc[f] = __builtin_amdgcn_mfma_f32_16x16x32_bf16(a, b, acc[f], 0, 0, 0);
        }
    }

    // endpoints + att regs for scoring (loaded after GEMM to cap VGPR pressure)
    int srcT[2], dstT[2];
#pragma unroll
    for (int t = 0; t < 2; ++t) {
        int r = (w >> 1) * 16 + t * 8 + (w & 1) * 4 + l4;
        srcT[t] = ei[e0 + r];
        dstT[t] = ei[N_EDGES + e0 + r];
    }
    float attreg[5][4];
#pragma unroll
    for (int it = 0; it < 5; ++it) {
#pragma unroll
        for (int k = 0; k < 2; ++k) {
            int g = (it * 16 + q16) * 2 + k;
            int head = g >> 4, s = g & 15;
            attreg[it][k * 2]     = att[head * 32 + s];
            attreg[it][k * 2 + 1] = att[head * 32 + 16 + s];
        }
    }

    // two spill/score passes of 32 rows each
#pragma unroll
    for (int t = 0; t < 2; ++t) {
        __syncthreads();                  // GEMM (t=0) / prev score reads (t=1) done
        if ((l4 >> 1) == t) {             // this lane owns rows of pass t
#pragma unroll
            for (int fp = 0; fp < 5; ++fp) {
                int head = (cq >> 5) + fp;
#pragma unroll
                for (int j = 0; j < 4; ++j) {
                    int slot = (w & 3) * 8 + (l4 & 1) * 4 + j;
                    *reinterpret_cast<unsigned int*>(
                        sE + slot * 648 + (head * 16 + l15) * 4) =
                        cvtpk(acc[2 * fp][j], acc[2 * fp + 1][j]);
                }
            }
        }
        __syncthreads();

        // score: wave w -> slots w*4+p4 (p4 = l4), 16 lanes per edge, 8B chunks
        const int src = srcT[t], dst = dstT[t];
        const int slot = w * 4 + l4;
        float hv[5];
#pragma unroll
        for (int it = 0; it < 5; ++it) {
            int chk = it * 16 + q16;      // 8B chunk 0..79
            uint2 ev  = *reinterpret_cast<const uint2*>(sE + slot * 648 + chk * 8);
            uint2 xlv = *reinterpret_cast<const uint2*>(y32 + (size_t)src * 320 + chk * 2);
            uint2 xrv = *reinterpret_cast<const uint2*>(y32 + (size_t)dst * 320 + 160 + chk * 2);
            float P1 = 0.f, P2 = 0.f;
            {
                float mlo = lo16(ev.x) + lo16(xlv.x) + lo16(xrv.x);
                float mhi = hi16(ev.x) + hi16(xlv.x) + hi16(xrv.x);
                P1 = fmaf(attreg[it][0], mlo, P1);
                P2 = fmaf(attreg[it][0], fabsf(mlo), P2);
                P1 = fmaf(attreg[it][1], mhi, P1);
                P2 = fmaf(attreg[it][1], fabsf(mhi), P2);
            }
            {
                float mlo = lo16(ev.y) + lo16(xlv.y) + lo16(xrv.y);
                float mhi = hi16(ev.y) + hi16(xlv.y) + hi16(xrv.y);
                P1 = fmaf(attreg[it][2], mlo, P1);
                P2 = fmaf(attreg[it][2], fabsf(mlo), P2);
                P1 = fmaf(attreg[it][3], mhi, P1);
                P2 = fmaf(attreg[it][3], fabsf(mhi), P2);
            }
            // att.lrelu(m) = 0.6*att.m + 0.4*att.|m| (slope 0.2)
            float v = 0.6f * P1 + 0.4f * P2;
            v += __shfl_xor(v, 1);
            v += __shfl_xor(v, 2);
            v += __shfl_xor(v, 4);
            hv[it] = v;                   // valid on lanes with (l&7)==0
        }
        if ((l & 7) == 0) {
            int hb = q16 >> 3;            // 0 or 1
            int e = e0 + (w >> 1) * 16 + t * 8 + (w & 1) * 4 + l4;
#pragma unroll
            for (int it = 0; it < 5; ++it) {
                float ex = __expf(hv[it]);   // |logit| small: no max-shift needed
                int head = it * 2 + hb;
                alphaE[(size_t)e * 10 + head] = ex;
                atomicAdd(&denom[(size_t)dst * 10 + head], ex);
            }
        }
    }
}

// ---------------- aggregation: accC[dst,c] += sum_h xl[src,h,c]*alpha_norm ----
// 2 edges per wave (32 lanes each); paired-u32 y loads; wv broadcast via shfl.
__global__ __launch_bounds__(256)
void k_agg(const float* __restrict__ alphaE, const float* __restrict__ denom,
           const unsigned short* __restrict__ y, const int* __restrict__ ei,
           float* __restrict__ accC)
{
    const int lane = threadIdx.x & 63;
    const int hw = lane >> 5;             // which edge of the pair
    const int hl = lane & 31;
    const int wid = (blockIdx.x * blockDim.x + threadIdx.x) >> 6;
    const int nw = (gridDim.x * blockDim.x) >> 6;
    const unsigned int* y32 = reinterpret_cast<const unsigned int*>(y);
#pragma unroll 2
    for (int ep = wid; ep < N_EDGES / 2; ep += nw) {
        int e = ep * 2 + hw;
        int src = ei[e];
        int dst = ei[N_EDGES + e];
        float wv = 0.f;
        if (hl < 10)
            wv = alphaE[(size_t)e * 10 + hl] / (denom[(size_t)dst * 10 + hl] + 1e-16f);
        float sLO = 0.f, sHI = 0.f;
#pragma unroll
        for (int k = 0; k < 5; ++k) {
            int g = k * 32 + hl;          // u32 index in xl block (0..159)
            float wh = __shfl(wv, (hw << 5) | (k * 2 + (hl >> 4)));
            unsigned int u = y32[(size_t)src * 320 + g];
            sLO = fmaf(wh, lo16(u), sLO);
            sHI = fmaf(wh, hi16(u), sHI);
        }
        // lanes hl and hl^16 cover the same col pair with complementary heads
        sLO += __shfl_xor(sLO, 16);
        sHI += __shfl_xor(sHI, 16);
        atomicAdd(&accC[(size_t)dst * 32 + hl], (hl & 16) ? sHI : sLO);
    }
}

// ---------------- per-node finish + per-graph mean pool ----------------
__global__ __launch_bounds__(256)
void k_pool(const float* __restrict__ accC, const float* __restrict__ bias_out,
            const int* __restrict__ batch, float* __restrict__ pooled,
            float* __restrict__ cnt)
{
    __shared__ float sm[G * C];
    __shared__ float smc[G];
    int tid = threadIdx.x;
    for (int i = tid; i < G * C; i += 256) sm[i] = 0.f;
    if (tid < G) smc[tid] = 0.f;
    __syncthreads();
    int base = blockIdx.x * 2048;
    for (int it = 0; it < 8; ++it) {
        int idx = base + it * 256 + tid;
        if (idx < N_NODES * C) {
            int n = idx >> 5, c = idx & 31;
            float v = accC[idx] * 0.1f + bias_out[c];
            v = fmaxf(v, 0.f);
            int gr = batch[n];
            atomicAdd(&sm[gr * C + c], v);
            if (c == 0) atomicAdd(&smc[gr], 1.f);
        }
    }
    __syncthreads();
    for (int i = tid; i < G * C; i += 256)
        if (sm[i] != 0.f) atomicAdd(&pooled[i], sm[i]);
    if (tid < G && smc[tid] != 0.f) atomicAdd(&cnt[tid], smc[tid]);
}

// ---------------- final tiny classifier ----------------
__global__ void k_final(const float* __restrict__ pooled, const float* __restrict__ cnt,
                        const float* __restrict__ Wlin, const float* __restrict__ blin,
                        float* __restrict__ out)
{
    int g = threadIdx.x;
    if (g >= G) return;
    float cg = fmaxf(cnt[g], 1.f);
    float s0 = blin[0], s1 = blin[1];
#pragma unroll
    for (int c = 0; c < C; ++c) {
        float p = pooled[g * C + c] / cg;
        s0 += p * Wlin[c];
        s1 += p * Wlin[C + c];
    }
    out[g * 2 + 0] = s0;
    out[g * 2 + 1] = s1;
}

extern "C" void kernel_launch(void* const* d_in, const int* in_sizes, int n_in,
                              void* d_out, int out_size, void* d_ws, size_t ws_size,
                              hipStream_t stream)
{
    const float* x         = (const float*)d_in[0];
    const float* edge_attr = (const float*)d_in[1];
    const float* bn_gamma  = (const float*)d_in[2];
    const float* bn_beta   = (const float*)d_in[3];
    const float* bn_mean   = (const float*)d_in[4];
    const float* bn_var    = (const float*)d_in[5];
    const float* Wl        = (const float*)d_in[6];
    const float* bl        = (const float*)d_in[7];
    const float* Wr        = (const float*)d_in[8];
    const float* br        = (const float*)d_in[9];
    const float* We        = (const float*)d_in[10];
    const float* att       = (const float*)d_in[11];
    const float* bias_out  = (const float*)d_in[12];
    const float* Wlin      = (const float*)d_in[13];
    const float* blin      = (const float*)d_in[14];
    const int* edge_index  = (const int*)d_in[15];
    const int* batch       = (const int*)d_in[16];
    float* out = (float*)d_out;

    char* ws = (char*)d_ws;
    unsigned short* Wh    = (unsigned short*)(ws + OFF_WH);
    float* scale          = (float*)(ws + OFF_SCALE);
    float* shift          = (float*)(ws + OFF_SHIFT);
    unsigned short* y     = (unsigned short*)(ws + OFF_Y);
    float* alphaE         = (float*)(ws + OFF_ALPHA);
    float* denom          = (float*)(ws + OFF_DENOM);
    float* accC           = (float*)(ws + OFF_ACC);
    float* pooled         = (float*)(ws + OFF_POOL);
    float* cnt            = (float*)(ws + OFF_CNT);

    k_init<<<1024, 256, 0, stream>>>(Wl, Wr, We, bn_gamma, bn_beta, bn_mean, bn_var,
                                     Wh, scale, shift, denom, accC, pooled, cnt);
    k_node_gemm<<<dim3(782, 2), 512, 0, stream>>>(x, Wh, scale, shift, bl, br, y);
    k_edge<<<6250, 512, 0, stream>>>(edge_attr, Wh, y, edge_index, att, alphaE, denom);
    k_agg<<<2048, 256, 0, stream>>>(alphaE, denom, y, edge_index, accC);
    k_pool<<<782, 256, 0, stream>>>(accC, bias_out, batch, pooled, cnt);
    k_final<<<1, 64, 0, stream>>>(pooled, cnt, Wlin, blin, out);
}

// Round 6
// 272.639 us; speedup vs baseline: 1.9691x; 1.9691x over previous
//
#include <hip/hip_runtime.h>
#include <hip/hip_bf16.h>

#define DI __device__ __forceinline__

typedef float f32x4 __attribute__((ext_vector_type(4)));
typedef short s16x8 __attribute__((ext_vector_type(8)));

constexpr int N_NODES = 50000;
constexpr int N_EDGES = 400000;
constexpr int G       = 64;
constexpr int C       = 32;
constexpr float BN_EPS = 1e-5f;

// ---------------- workspace layout (bytes) ----------------
constexpr size_t OFF_WH    = 0;                                   // [960][128] bf16 (Wl,Wr,We)
constexpr size_t OFF_SCALE = 245760;                              // [128] f32
constexpr size_t OFF_SHIFT = OFF_SCALE + 512;                     // [128] f32
constexpr size_t OFF_Y     = OFF_SHIFT + 512;                     // [N][640] bf16 (xl|xr, PAIRED)
constexpr size_t OFF_ALPHA = OFF_Y + (size_t)N_NODES * 640 * 2;   // [E][10] f32 (exp(alpha))
constexpr size_t OFF_DENOM = OFF_ALPHA + (size_t)N_EDGES * 10 * 4;// [N][10] f32
constexpr size_t OFF_ACC   = OFF_DENOM + (size_t)N_NODES * 10 * 4;// [N][32] f32
constexpr size_t OFF_POOL  = OFF_ACC + (size_t)N_NODES * 32 * 4;  // [64][32] f32
constexpr size_t OFF_CNT   = OFF_POOL + (size_t)G * C * 4;        // [64] f32

// y PAIRED layout: u32[n*320 + headg*16 + s] holds bf16 cols (headg*32+s, headg*32+16+s),
// headg 0..9 = xl heads, 10..19 = xr heads.

DI float bf2f(unsigned short u) {
    unsigned int x = ((unsigned int)u) << 16;
    float f; __builtin_memcpy(&f, &x, 4); return f;
}
DI unsigned short f2bf(float f) {   // round-to-nearest-even (finite inputs)
    unsigned int x; __builtin_memcpy(&x, &f, 4);
    x += 0x7FFFu + ((x >> 16) & 1u);
    return (unsigned short)(x >> 16);
}
DI float lo16(unsigned int u) {
    unsigned int x = u << 16; float f; __builtin_memcpy(&f, &x, 4); return f;
}
DI float hi16(unsigned int u) {
    unsigned int x = u & 0xffff0000u; float f; __builtin_memcpy(&f, &x, 4); return f;
}
DI unsigned int cvtpk(float a, float b) {  // v_cvt_pk_bf16_f32: lo=a, hi=b
    unsigned int r;
    asm("v_cvt_pk_bf16_f32 %0, %1, %2" : "=v"(r) : "v"(a), "v"(b));
    return r;
}
// XOR swizzle inside a 256B row (A tile: row stride 256B)
DI int swzA(int row, int kb) { return row * 256 + (kb ^ ((row & 7) << 4)); }

// ---------------- init ----------------
__global__ void k_init(const float* __restrict__ Wl, const float* __restrict__ Wr,
                       const float* __restrict__ We, const float* __restrict__ gamma,
                       const float* __restrict__ beta, const float* __restrict__ mean,
                       const float* __restrict__ var,
                       unsigned short* __restrict__ Wh, float* __restrict__ scale,
                       float* __restrict__ shift, float* __restrict__ denom,
                       float* __restrict__ accC, float* __restrict__ pooled,
                       float* __restrict__ cnt)
{
    int idx0 = blockIdx.x * blockDim.x + threadIdx.x;
    int stride = gridDim.x * blockDim.x;
    for (int i = idx0; i < 960 * 128; i += stride) {
        float v;
        if (i < 320 * 128)      v = Wl[i];
        else if (i < 640 * 128) v = Wr[i - 320 * 128];
        else                    v = We[i - 640 * 128];
        Wh[i] = f2bf(v);
    }
    for (int i = idx0; i < 128; i += stride) {
        float sc = gamma[i] * rsqrtf(var[i] + BN_EPS);
        scale[i] = sc;
        shift[i] = beta[i] - mean[i] * sc;
    }
    for (int i = idx0; i < N_NODES * 10; i += stride) denom[i] = 0.f;
    for (int i = idx0; i < N_NODES * 32; i += stride) accC[i] = 0.f;
    for (int i = idx0; i < G * C; i += stride) pooled[i] = 0.f;
    for (int i = idx0; i < G; i += stride) cnt[i] = 0.f;
}

// B-chunk LDS layout (20KB per K=32 chunk): slot (col,k16') at byte col*64+k16'*16
// holds global k-frag k16 = k16' ^ ((col>>1)&3).  Writes: linear (id*16).
// Reads: 16 cols x fixed l4 -> banks (col&1)*16 + perm*4, 2-way max.

// ---------------- node GEMM: y[n] = bn(x) @ [Wl;Wr].T + [bl;br] (paired bf16)
__global__ __launch_bounds__(512)
void k_node_gemm(const float* __restrict__ x, const unsigned short* __restrict__ Wh,
                 const float* __restrict__ scale, const float* __restrict__ shift,
                 const float* __restrict__ bl, const float* __restrict__ br,
                 unsigned short* __restrict__ y)
{
    __shared__ unsigned char smem[36864];
    unsigned char* sA = smem;             // [64][256B] swizzled
    unsigned char* sB = smem + 16384;     // B chunk, 20KB
    const int tid = threadIdx.x;
    const int n0 = blockIdx.x * 64;
    const int ch = blockIdx.y;            // 0: Wl half, 1: Wr half
    const int wrow0 = ch * 320;

    // stage A (x with BN fused), fp32 -> bf16
#pragma unroll
    for (int it = 0; it < 4; ++it) {
        int c = tid + it * 512;           // 0..2047
        int row = c >> 5, q = c & 31;
        int n = n0 + row;
        float4 v = make_float4(0.f, 0.f, 0.f, 0.f);
        if (n < N_NODES) v = *reinterpret_cast<const float4*>(x + (size_t)n * 128 + q * 4);
        float x0 = v.x * scale[q * 4 + 0] + shift[q * 4 + 0];
        float x1 = v.y * scale[q * 4 + 1] + shift[q * 4 + 1];
        float x2 = v.z * scale[q * 4 + 2] + shift[q * 4 + 2];
        float x3 = v.w * scale[q * 4 + 3] + shift[q * 4 + 3];
        uint2 pk = make_uint2(cvtpk(x0, x1), cvtpk(x2, x3));
        *reinterpret_cast<uint2*>(sA + swzA(row, q * 8)) = pk;
    }

    const int w = tid >> 6, l = tid & 63;
    const int rw = (w & 3) * 16;
    const int cq = (w >> 2) * 160;
    const int l15 = l & 15, l4 = l >> 4;

    f32x4 acc[10];
#pragma unroll
    for (int f = 0; f < 10; ++f) acc[f] = (f32x4){0.f, 0.f, 0.f, 0.f};

    for (int kq = 0; kq < 4; ++kq) {
        __syncthreads();                  // A ready (kq=0) / prev MFMA done (kq>0)
#pragma unroll
        for (int it = 0; it < 3; ++it) {
            int id = tid + it * 512;      // 0..1535, valid < 1280
            if (id < 1280) {
                int col = id >> 2;
                int k16 = (id & 3) ^ ((col >> 1) & 3);
                uint4 v = *reinterpret_cast<const uint4*>(
                    Wh + (size_t)(wrow0 + col) * 128 + kq * 32 + k16 * 8);
                *reinterpret_cast<uint4*>(sB + id * 16) = v;
            }
        }
        __syncthreads();
        s16x8 a = *reinterpret_cast<const s16x8*>(sA + swzA(rw + l15, kq * 64 + l4 * 16));
#pragma unroll
        for (int f = 0; f < 10; ++f) {
            int col = cq + f * 16 + l15;
            s16x8 b = *reinterpret_cast<const s16x8*>(
                sB + col * 64 + ((l4 ^ ((col >> 1) & 3)) << 4));
            acc[f] = __builtin_amdgcn_mfma_f32_16x16x32_bf16(a, b, acc[f], 0, 0, 0);
        }
    }

    const float* bias = ch ? br : bl;
    unsigned int* y32 = reinterpret_cast<unsigned int*>(y);
#pragma unroll
    for (int fp = 0; fp < 5; ++fp) {
        int lc0 = cq + fp * 32 + l15;     // low col of the pair within this half
        float b0 = bias[lc0], b1 = bias[lc0 + 16];
        int headg = ch * 10 + (cq >> 5) + fp;
#pragma unroll
        for (int j = 0; j < 4; ++j) {
            int n = n0 + rw + l4 * 4 + j;
            if (n < N_NODES)
                y32[(size_t)n * 320 + headg * 16 + l15] =
                    cvtpk(acc[2 * fp][j] + b0, acc[2 * fp + 1][j] + b1);
        }
    }
}

// ---------------- edge GEMM + GATv2 scoring ----------------
// LDS 41,472B -> 3 blocks/CU. GEMM: A 16KB + B-chunk 20KB.
// After GEMM the whole buffer becomes the ea spill [64][648B].
__global__ __launch_bounds__(512)
void k_edge(const float* __restrict__ eattr, const unsigned short* __restrict__ Wh,
            const unsigned short* __restrict__ y, const int* __restrict__ ei,
            const float* __restrict__ att, float* __restrict__ alphaE,
            float* __restrict__ denom)
{
    __shared__ unsigned char smem[64 * 648];      // 41472 B
    unsigned char* sA = smem;                     // A tile (16KB) during GEMM
    unsigned char* sB = smem + 16384;             // B chunk (20KB) during GEMM
    unsigned char* sE = smem;                     // ea spill, after GEMM
    const int tid = threadIdx.x;
    const int e0 = blockIdx.x * 64;
    const int w = tid >> 6, l = tid & 63;
    const int rw = (w & 3) * 16;
    const int cq = (w >> 2) * 160;
    const int l15 = l & 15, l4 = l >> 4;

    // stage A (edge_attr fp32 -> bf16); E = 6250*64 exactly, no bounds needed
#pragma unroll
    for (int it = 0; it < 4; ++it) {
        int c = tid + it * 512;
        int row = c >> 5, q = c & 31;
        float4 v = *reinterpret_cast<const float4*>(eattr + (size_t)(e0 + row) * 128 + q * 4);
        uint2 pk = make_uint2(cvtpk(v.x, v.y), cvtpk(v.z, v.w));
        *reinterpret_cast<uint2*>(sA + swzA(row, q * 8)) = pk;
    }

    f32x4 acc[10];
#pragma unroll
    for (int f = 0; f < 10; ++f) acc[f] = (f32x4){0.f, 0.f, 0.f, 0.f};

    for (int kq = 0; kq < 4; ++kq) {
        __syncthreads();                  // A ready (kq=0) / prev MFMA done (kq>0)
#pragma unroll
        for (int it = 0; it < 3; ++it) {
            int id = tid + it * 512;      // 0..1535, valid < 1280
            if (id < 1280) {
                int col = id >> 2;
                int k16 = (id & 3) ^ ((col >> 1) & 3);
                uint4 v = *reinterpret_cast<const uint4*>(
                    Wh + (size_t)(640 + col) * 128 + kq * 32 + k16 * 8);
                *reinterpret_cast<uint4*>(sB + id * 16) = v;
            }
        }
        __syncthreads();
        s16x8 a = *reinterpret_cast<const s16x8*>(sA + swzA(rw + l15, kq * 64 + l4 * 16));
#pragma unroll
        for (int f = 0; f < 10; ++f) {
            int col = cq + f * 16 + l15;
            s16x8 b = *reinterpret_cast<const s16x8*>(
                sB + col * 64 + ((l4 ^ ((col >> 1) & 3)) << 4));
            acc[f] = __builtin_amdgcn_mfma_f32_16x16x32_bf16(a, b, acc[f], 0, 0, 0);
        }
    }

    // edge endpoints for the scoring phase (issue early, hide under spill)
    const int p = l >> 3, q = l & 7;
    const int e = e0 + w * 8 + p;
    const int src = ei[e];
    const int dst = ei[N_EDGES + e];

    __syncthreads();   // all waves done reading sA/sB -> safe to overwrite as sE

    // spill ea as paired-bf16 u32s, row stride 648B
#pragma unroll
    for (int fp = 0; fp < 5; ++fp) {
        int head = (cq >> 5) + fp;        // 0..9
#pragma unroll
        for (int j = 0; j < 4; ++j) {
            int row = rw + l4 * 4 + j;
            *reinterpret_cast<unsigned int*>(sE + row * 648 + (head * 16 + l15) * 4) =
                cvtpk(acc[2 * fp][j], acc[2 * fp + 1][j]);
        }
    }
    __syncthreads();

    // att in PAIRED order matching the 16B chunks this lane reads
    float attreg[5][8];
#pragma unroll
    for (int it = 0; it < 5; ++it) {
        int head = it * 2 + (q >> 2), c4 = q & 3;
#pragma unroll
        for (int i = 0; i < 8; ++i)
            attreg[it][i] = att[head * 32 + c4 * 4 + (i >> 1) + (i & 1) * 16];
    }

    const unsigned int* y32 = reinterpret_cast<const unsigned int*>(y);
    // ---- scoring: 64 lanes = 8 edges x 8 lanes, 5 iterations of 16B chunks ----
    float hv[5];
#pragma unroll
    for (int it = 0; it < 5; ++it) {
        int ch = it * 8 + q;              // chunk 0..39
        s16x8 ev = *reinterpret_cast<const s16x8*>(sE + (w * 8 + p) * 648 + ch * 16);
        uint4 xlv = *reinterpret_cast<const uint4*>(y32 + (size_t)src * 320 + ch * 4);
        uint4 xrv = *reinterpret_cast<const uint4*>(y32 + (size_t)dst * 320 + 160 + ch * 4);
        const unsigned int* eu  = reinterpret_cast<const unsigned int*>(&ev);
        const unsigned int* xlu = reinterpret_cast<const unsigned int*>(&xlv);
        const unsigned int* xru = reinterpret_cast<const unsigned int*>(&xrv);
        float P1 = 0.f, P2 = 0.f;
#pragma unroll
        for (int i = 0; i < 4; ++i) {
            float mlo = lo16(eu[i]) + lo16(xlu[i]) + lo16(xru[i]);
            float mhi = hi16(eu[i]) + hi16(xlu[i]) + hi16(xru[i]);
            P1 = fmaf(attreg[it][2 * i],     mlo, P1);
            P2 = fmaf(attreg[it][2 * i],     fabsf(mlo), P2);
            P1 = fmaf(attreg[it][2 * i + 1], mhi, P1);
            P2 = fmaf(attreg[it][2 * i + 1], fabsf(mhi), P2);
        }
        // att.lrelu(m) = 0.6*att.m + 0.4*att.|m| (slope 0.2)
        float v = 0.6f * P1 + 0.4f * P2;
        v += __shfl_xor(v, 1);
        v += __shfl_xor(v, 2);
        hv[it] = v;                       // valid on lanes with (l&3)==0
    }
    if ((l & 3) == 0) {
        int par = (l >> 2) & 1;
#pragma unroll
        for (int it = 0; it < 5; ++it) {
            float ex = __expf(hv[it]);    // |logit| small: no max-shift needed
            int head = it * 2 + par;
            alphaE[(size_t)e * 10 + head] = ex;
            atomicAdd(&denom[(size_t)dst * 10 + head], ex);
        }
    }
}

// ---------------- aggregation: accC[dst,c] += sum_h xl[src,h,c]*alpha_norm ----
// 2 edges per wave (32 lanes each); paired-u32 y loads; wv broadcast via shfl.
__global__ __launch_bounds__(256)
void k_agg(const float* __restrict__ alphaE, const float* __restrict__ denom,
           const unsigned short* __restrict__ y, const int* __restrict__ ei,
           float* __restrict__ accC)
{
    const int lane = threadIdx.x & 63;
    const int hw = lane >> 5;             // which edge of the pair
    const int hl = lane & 31;
    const int wid = (blockIdx.x * blockDim.x + threadIdx.x) >> 6;
    const int nw = (gridDim.x * blockDim.x) >> 6;
    const unsigned int* y32 = reinterpret_cast<const unsigned int*>(y);
#pragma unroll 2
    for (int ep = wid; ep < N_EDGES / 2; ep += nw) {
        int e = ep * 2 + hw;
        int src = ei[e];
        int dst = ei[N_EDGES + e];
        float wv = 0.f;
        if (hl < 10)
            wv = alphaE[(size_t)e * 10 + hl] / (denom[(size_t)dst * 10 + hl] + 1e-16f);
        float sLO = 0.f, sHI = 0.f;
#pragma unroll
        for (int k = 0; k < 5; ++k) {
            int g = k * 32 + hl;          // u32 index in xl block (0..159)
            float wh = __shfl(wv, (hw << 5) | (k * 2 + (hl >> 4)));
            unsigned int u = y32[(size_t)src * 320 + g];
            sLO = fmaf(wh, lo16(u), sLO);
            sHI = fmaf(wh, hi16(u), sHI);
        }
        // lanes hl and hl^16 cover the same col pair with complementary heads
        sLO += __shfl_xor(sLO, 16);
        sHI += __shfl_xor(sHI, 16);
        atomicAdd(&accC[(size_t)dst * 32 + hl], (hl & 16) ? sHI : sLO);
    }
}

// ---------------- per-node finish + per-graph mean pool ----------------
__global__ __launch_bounds__(256)
void k_pool(const float* __restrict__ accC, const float* __restrict__ bias_out,
            const int* __restrict__ batch, float* __restrict__ pooled,
            float* __restrict__ cnt)
{
    __shared__ float sm[G * C];
    __shared__ float smc[G];
    int tid = threadIdx.x;
    for (int i = tid; i < G * C; i += 256) sm[i] = 0.f;
    if (tid < G) smc[tid] = 0.f;
    __syncthreads();
    int base = blockIdx.x * 2048;
    for (int it = 0; it < 8; ++it) {
        int idx = base + it * 256 + tid;
        if (idx < N_NODES * C) {
            int n = idx >> 5, c = idx & 31;
            float v = accC[idx] * 0.1f + bias_out[c];
            v = fmaxf(v, 0.f);
            int gr = batch[n];
            atomicAdd(&sm[gr * C + c], v);
            if (c == 0) atomicAdd(&smc[gr], 1.f);
        }
    }
    __syncthreads();
    for (int i = tid; i < G * C; i += 256)
        if (sm[i] != 0.f) atomicAdd(&pooled[i], sm[i]);
    if (tid < G && smc[tid] != 0.f) atomicAdd(&cnt[tid], smc[tid]);
}

// ---------------- final tiny classifier ----------------
__global__ void k_final(const float* __restrict__ pooled, const float* __restrict__ cnt,
                        const float* __restrict__ Wlin, const float* __restrict__ blin,
                        float* __restrict__ out)
{
    int g = threadIdx.x;
    if (g >= G) return;
    float cg = fmaxf(cnt[g], 1.f);
    float s0 = blin[0], s1 = blin[1];
#pragma unroll
    for (int c = 0; c < C; ++c) {
        float p = pooled[g * C + c] / cg;
        s0 += p * Wlin[c];
        s1 += p * Wlin[C + c];
    }
    out[g * 2 + 0] = s0;
    out[g * 2 + 1] = s1;
}

extern "C" void kernel_launch(void* const* d_in, const int* in_sizes, int n_in,
                              void* d_out, int out_size, void* d_ws, size_t ws_size,
                              hipStream_t stream)
{
    const float* x         = (const float*)d_in[0];
    const float* edge_attr = (const float*)d_in[1];
    const float* bn_gamma  = (const float*)d_in[2];
    const float* bn_beta   = (const float*)d_in[3];
    const float* bn_mean   = (const float*)d_in[4];
    const float* bn_var    = (const float*)d_in[5];
    const float* Wl        = (const float*)d_in[6];
    const float* bl        = (const float*)d_in[7];
    const float* Wr        = (const float*)d_in[8];
    const float* br        = (const float*)d_in[9];
    const float* We        = (const float*)d_in[10];
    const float* att       = (const float*)d_in[11];
    const float* bias_out  = (const float*)d_in[12];
    const float* Wlin      = (const float*)d_in[13];
    const float* blin      = (const float*)d_in[14];
    const int* edge_index  = (const int*)d_in[15];
    const int* batch       = (const int*)d_in[16];
    float* out = (float*)d_out;

    char* ws = (char*)d_ws;
    unsigned short* Wh    = (unsigned short*)(ws + OFF_WH);
    float* scale          = (float*)(ws + OFF_SCALE);
    float* shift          = (float*)(ws + OFF_SHIFT);
    unsigned short* y     = (unsigned short*)(ws + OFF_Y);
    float* alphaE         = (float*)(ws + OFF_ALPHA);
    float* denom          = (float*)(ws + OFF_DENOM);
    float* accC           = (float*)(ws + OFF_ACC);
    float* pooled         = (float*)(ws + OFF_POOL);
    float* cnt            = (float*)(ws + OFF_CNT);

    k_init<<<1024, 256, 0, stream>>>(Wl, Wr, We, bn_gamma, bn_beta, bn_mean, bn_var,
                                     Wh, scale, shift, denom, accC, pooled, cnt);
    k_node_gemm<<<dim3(782, 2), 512, 0, stream>>>(x, Wh, scale, shift, bl, br, y);
    k_edge<<<6250, 512, 0, stream>>>(edge_attr, Wh, y, edge_index, att, alphaE, denom);
    k_agg<<<2048, 256, 0, stream>>>(alphaE, denom, y, edge_index, accC);
    k_pool<<<782, 256, 0, stream>>>(accC, bias_out, batch, pooled, cnt);
    k_final<<<1, 64, 0, stream>>>(pooled, cnt, Wlin, blin, out);
}